// Round 1
// baseline (358.323 us; speedup 1.0000x reference)
//
#include <hip/hip_runtime.h>
#include <stdint.h>

// ---------------------------------------------------------------------------
// ThirdOrderAttention: B=1, N=256, C=512, H=8, D=64
// scores[i,j,k] = sum_d q[i,d] kj[j,d] kk[k,d] * 0.125 ; softmax over (j,k)
// y[i,d] = sum_jk w * vj[j,d]*vk[k,d];  out = (y headcat) @ W_out + b_out
// Strategy: flash attention over virtual L=65536 KV (K'=kj*kk, V'=vj*vk),
// bf16 MFMA, no max-subtraction (scores tiny), fp32 atomics for partials.
// ---------------------------------------------------------------------------

typedef __attribute__((ext_vector_type(4))) float f32x4;
typedef __attribute__((ext_vector_type(4))) short s16x4;
typedef __attribute__((ext_vector_type(8))) short s16x8;

#define H_ 8
#define N_ 256
#define D_ 64
#define C_ 512
#define NC5 2560
#define SCALE_LOG2E 0.1803368801111204f  // 0.125 * log2(e): P = exp2(S')

// ----- bf16 helpers --------------------------------------------------------
__device__ __forceinline__ unsigned short f2bf_rne(float x) {
  union { float f; unsigned u; } a; a.f = x;
  unsigned r = a.u + 0x7fffu + ((a.u >> 16) & 1u);
  return (unsigned short)(r >> 16);
}

__device__ __forceinline__ unsigned pk_bf16(float a, float b) {
#if __has_builtin(__builtin_amdgcn_cvt_pk_bf16_f32)
  typedef __attribute__((ext_vector_type(2))) __bf16 bf16x2;
  union { bf16x2 v; unsigned u; } u;
  u.v = __builtin_amdgcn_cvt_pk_bf16_f32(a, b);
  return u.u;
#else
  return (unsigned)f2bf_rne(a) | ((unsigned)f2bf_rne(b) << 16);
#endif
}

// ----- MFMA wrappers -------------------------------------------------------
__device__ __forceinline__ f32x4 mfma32(s16x8 a, s16x8 b, f32x4 c) {
  return __builtin_amdgcn_mfma_f32_16x16x32_bf16(a, b, c, 0, 0, 0);
}

__device__ __forceinline__ f32x4 mfma16(s16x4 a, s16x4 b, f32x4 c) {
#if __has_builtin(__builtin_amdgcn_mfma_f32_16x16x16bf16_1k)
  return __builtin_amdgcn_mfma_f32_16x16x16bf16_1k(a, b, c, 0, 0, 0);
#else
  // fallback: raw instruction; s_nops guard MFMA<->VALU hazards conservatively
  asm volatile("s_nop 1\n\t"
               "v_mfma_f32_16x16x16_bf16 %0, %1, %2, %0\n\t"
               "s_nop 7\n\t"
               "s_nop 2"
               : "+v"(c) : "v"(a), "v"(b));
  return c;
#endif
}

// ---------------------------------------------------------------------------
// Kernel 1: projection GEMM  p = x[256,512] @ W_att[512,2560] + b_att
// Epilogue routes columns into per-head q (bf16, pre-scaled), kj, kk, vj, vkT.
// BM=32, BN=64, BK=16; 256 threads; micro-tile 4x2. Grid (40, 8).
// ---------------------------------------------------------------------------
__global__ __launch_bounds__(256) void proj_kernel(
    const float* __restrict__ x, const float* __restrict__ W,
    const float* __restrict__ b,
    unsigned short* __restrict__ qB, float* __restrict__ kj,
    float* __restrict__ kk, float* __restrict__ vj, float* __restrict__ vkT) {
  __shared__ float As[16][33];
  __shared__ float Bs[16][68];
  const int bx = blockIdx.x;  // 40 col tiles of 64
  const int by = blockIdx.y;  // 8 row tiles of 32
  const int tid = threadIdx.x;
  const int tr = (tid >> 5) * 4;  // row 0..28
  const int tc = (tid & 31) * 2;  // col 0..62
  float accv[4][2] = {};

  for (int k0 = 0; k0 < C_; k0 += 16) {
#pragma unroll
    for (int t = 0; t < 2; ++t) {
      int e = tid + t * 256;
      int r = e >> 4, kq = e & 15;
      As[kq][r] = x[(by * 32 + r) * C_ + k0 + kq];
    }
    {
      int br = tid >> 4, bc = (tid & 15) * 4;
      *(f32x4*)&Bs[br][bc] = *(const f32x4*)&W[(k0 + br) * NC5 + bx * 64 + bc];
    }
    __syncthreads();
#pragma unroll
    for (int kq = 0; kq < 16; ++kq) {
      float a0 = As[kq][tr + 0], a1 = As[kq][tr + 1];
      float a2 = As[kq][tr + 2], a3 = As[kq][tr + 3];
      float b0 = Bs[kq][tc + 0], b1 = Bs[kq][tc + 1];
      accv[0][0] += a0 * b0; accv[0][1] += a0 * b1;
      accv[1][0] += a1 * b0; accv[1][1] += a1 * b1;
      accv[2][0] += a2 * b0; accv[2][1] += a2 * b1;
      accv[3][0] += a3 * b0; accv[3][1] += a3 * b1;
    }
    __syncthreads();
  }

#pragma unroll
  for (int rr = 0; rr < 4; ++rr)
#pragma unroll
    for (int cc = 0; cc < 2; ++cc) {
      int i = by * 32 + tr + rr;
      int col = bx * 64 + tc + cc;
      float v = accv[rr][cc] + b[col];
      int h = col / 320;
      int rm = col % 320;
      int part = rm >> 6;
      int d = rm & 63;
      int idx = (h * N_ + i) * D_ + d;
      if (part == 0)      qB[idx] = f2bf_rne(v * SCALE_LOG2E);
      else if (part == 1) kj[idx] = v;
      else if (part == 2) kk[idx] = v;
      else if (part == 3) vj[idx] = v;
      else                vkT[(h * D_ + d) * N_ + i] = v;
    }
}

// ---------------------------------------------------------------------------
// Kernel 2: fused third-order flash attention.
// Grid (8 heads, 64 chunks of 4 j). Block 256 = 4 waves, wave owns 64 i rows.
// Per (j, k0) subtile of 64 t = (j,k):
//   S^T[t,i] = E[t,:] . Q[i,:]   via mfma 16x16x32 (A=E built in-regs)
//   P = exp2(S'); C-layout of S^T IS the B-layout of mfma 16x16x16 -> PV gemm
//   Y^T[d,i] += F[d,t-slice] @ P^T  via mfma 16x16x16 (A=F built in-regs)
// No LDS, no barriers. fp32 atomicAdd partials into y_acc/l_acc.
// ---------------------------------------------------------------------------
__global__ __launch_bounds__(256, 2) void flash3_kernel(
    const unsigned short* __restrict__ qB,  // [H][N][D] bf16 (pre-scaled)
    const float* __restrict__ kjF,          // [H][N][D]
    const float* __restrict__ kkF,          // [H][N][D]
    const float* __restrict__ vjF,          // [H][N][D]
    const float* __restrict__ vkT,          // [H][D][N]
    float* __restrict__ y_acc,              // [H][N][D]
    float* __restrict__ l_acc) {            // [H][N]
  const int h = blockIdx.x;
  const int ch = blockIdx.y;  // 64 chunks * 4 j
  const int wave = threadIdx.x >> 6;
  const int lane = threadIdx.x & 63;
  const int q = lane >> 4;
  const int c = lane & 15;
  const int i0 = wave * 64;

  const unsigned short* qh = qB + h * (N_ * D_);
  const float* kjh = kjF + h * (N_ * D_);
  const float* kkh = kkF + h * (N_ * D_);
  const float* vjh = vjF + h * (N_ * D_);
  const float* vkh = vkT + h * (D_ * N_);

  // Q B-fragments for the S^T gemm: B[k=d=q*8+j'][n=i=lane&15], per 32-d step
  s16x8 qf[4][2];
#pragma unroll
  for (int nb = 0; nb < 4; ++nb)
#pragma unroll
    for (int ks = 0; ks < 2; ++ks)
      qf[nb][ks] =
          *(const s16x8*)(qh + (i0 + nb * 16 + c) * D_ + ks * 32 + q * 8);

  f32x4 acc[4][4];  // Y^T tiles: [mb over d][nb over i]
#pragma unroll
  for (int mb = 0; mb < 4; ++mb)
#pragma unroll
    for (int nb = 0; nb < 4; ++nb) acc[mb][nb] = (f32x4){0.f, 0.f, 0.f, 0.f};
  float lac[4] = {0.f, 0.f, 0.f, 0.f};

  for (int jj = 0; jj < 4; ++jj) {
    const int j = ch * 4 + jj;
    // hoist kj row segments (d = ks*32 + q*8 + 0..7) and vj scalars
    const f32x4 kj0a = *(const f32x4*)(kjh + j * D_ + q * 8);
    const f32x4 kj0b = *(const f32x4*)(kjh + j * D_ + q * 8 + 4);
    const f32x4 kj1a = *(const f32x4*)(kjh + j * D_ + 32 + q * 8);
    const f32x4 kj1b = *(const f32x4*)(kjh + j * D_ + 32 + q * 8 + 4);
    float vjv[4];
#pragma unroll
    for (int mb = 0; mb < 4; ++mb) vjv[mb] = vjh[j * D_ + mb * 16 + c];

    for (int k0 = 0; k0 < N_; k0 += 64) {
      unsigned pb[4][4][2];  // P bf16 pairs: [t-slice][nb][dword]
#pragma unroll
      for (int mb = 0; mb < 4; ++mb) {
        // E A-frag: m = t = k0+mb*16+c ; k = d = ks*32 + q*8 + 0..7
        const int trow = k0 + mb * 16 + c;
        const float* kkp = kkh + trow * D_;
        f32x4 k0a = *(const f32x4*)(kkp + q * 8);
        f32x4 k0b = *(const f32x4*)(kkp + q * 8 + 4);
        f32x4 k1a = *(const f32x4*)(kkp + 32 + q * 8);
        f32x4 k1b = *(const f32x4*)(kkp + 32 + q * 8 + 4);
        union { unsigned u[4]; s16x8 v; } ea0, ea1;
        ea0.u[0] = pk_bf16(k0a.x * kj0a.x, k0a.y * kj0a.y);
        ea0.u[1] = pk_bf16(k0a.z * kj0a.z, k0a.w * kj0a.w);
        ea0.u[2] = pk_bf16(k0b.x * kj0b.x, k0b.y * kj0b.y);
        ea0.u[3] = pk_bf16(k0b.z * kj0b.z, k0b.w * kj0b.w);
        ea1.u[0] = pk_bf16(k1a.x * kj1a.x, k1a.y * kj1a.y);
        ea1.u[1] = pk_bf16(k1a.z * kj1a.z, k1a.w * kj1a.w);
        ea1.u[2] = pk_bf16(k1b.x * kj1b.x, k1b.y * kj1b.y);
        ea1.u[3] = pk_bf16(k1b.z * kj1b.z, k1b.w * kj1b.w);

        f32x4 st[4];
#pragma unroll
        for (int nb = 0; nb < 4; ++nb) {
          f32x4 z = (f32x4){0.f, 0.f, 0.f, 0.f};
          z = mfma32(ea0.v, qf[nb][0], z);
          z = mfma32(ea1.v, qf[nb][1], z);
          st[nb] = z;
        }
#pragma unroll
        for (int nb = 0; nb < 4; ++nb) {
          float p0 = __builtin_exp2f(st[nb].x);
          float p1 = __builtin_exp2f(st[nb].y);
          float p2 = __builtin_exp2f(st[nb].z);
          float p3 = __builtin_exp2f(st[nb].w);
          lac[nb] += (p0 + p1) + (p2 + p3);
          pb[mb][nb][0] = pk_bf16(p0, p1);
          pb[mb][nb][1] = pk_bf16(p2, p3);
        }
      }
      // PV gemm: Y^T[d,i] += F[d, t16] @ P^T[t16, i], K=16 per step
#pragma unroll
      for (int kt = 0; kt < 4; ++kt) {
        s16x4 ft[4];
#pragma unroll
        for (int mb = 0; mb < 4; ++mb) {
          // F A-frag: m = d = mb*16+c ; k = t = kt*16 + q*4 + 0..3
          const float* vp = vkh + (mb * 16 + c) * N_ + k0 + kt * 16 + q * 4;
          f32x4 v = *(const f32x4*)vp;
          float s = vjv[mb];
          union { unsigned u[2]; s16x4 v4; } t;
          t.u[0] = pk_bf16(v.x * s, v.y * s);
          t.u[1] = pk_bf16(v.z * s, v.w * s);
          ft[mb] = t.v4;
        }
#pragma unroll
        for (int mb = 0; mb < 4; ++mb)
#pragma unroll
          for (int nb = 0; nb < 4; ++nb) {
            union { unsigned u[2]; s16x4 v4; } p;
            p.u[0] = pb[kt][nb][0];
            p.u[1] = pb[kt][nb][1];
            acc[mb][nb] = mfma16(ft[mb], p.v4, acc[mb][nb]);
          }
      }
    }
  }

  // epilogue: l partial (reduce over quads), then Y partial
#pragma unroll
  for (int nb = 0; nb < 4; ++nb) {
    float v = lac[nb];
    v += __shfl_xor(v, 16);
    v += __shfl_xor(v, 32);
    if (q == 0) atomicAdd(l_acc + h * N_ + i0 + nb * 16 + c, v);
  }
#pragma unroll
  for (int mb = 0; mb < 4; ++mb)
#pragma unroll
    for (int nb = 0; nb < 4; ++nb) {
      int i = i0 + nb * 16 + c;
      int d = mb * 16 + q * 4;
      float* p = y_acc + (h * N_ + i) * D_ + d;
      atomicAdd(p + 0, acc[mb][nb].x);
      atomicAdd(p + 1, acc[mb][nb].y);
      atomicAdd(p + 2, acc[mb][nb].z);
      atomicAdd(p + 3, acc[mb][nb].w);
    }
}

// ---------------------------------------------------------------------------
// Kernel 3: normalize + head re-interleave: yn[i][h*64+d] = y_acc/l
// ---------------------------------------------------------------------------
__global__ __launch_bounds__(256) void norm_kernel(
    const float* __restrict__ y_acc, const float* __restrict__ l_acc,
    float* __restrict__ yn) {
  int idx = blockIdx.x * 256 + threadIdx.x;  // 131072
  int h = idx >> 14;
  int i = (idx >> 6) & 255;
  int d = idx & 63;
  yn[i * C_ + h * D_ + d] = y_acc[idx] / l_acc[h * N_ + i];
}

// ---------------------------------------------------------------------------
// Kernel 4: out = yn[256,512] @ W_out[512,512] + b_out   (fp32, grid (8,8))
// ---------------------------------------------------------------------------
__global__ __launch_bounds__(256) void out_gemm(
    const float* __restrict__ A, const float* __restrict__ W,
    const float* __restrict__ b, float* __restrict__ out) {
  __shared__ float As[16][33];
  __shared__ float Bs[16][68];
  const int bx = blockIdx.x;  // 8 col tiles of 64
  const int by = blockIdx.y;  // 8 row tiles of 32
  const int tid = threadIdx.x;
  const int tr = (tid >> 5) * 4;
  const int tc = (tid & 31) * 2;
  float accv[4][2] = {};

  for (int k0 = 0; k0 < C_; k0 += 16) {
#pragma unroll
    for (int t = 0; t < 2; ++t) {
      int e = tid + t * 256;
      int r = e >> 4, kq = e & 15;
      As[kq][r] = A[(by * 32 + r) * C_ + k0 + kq];
    }
    {
      int br = tid >> 4, bc = (tid & 15) * 4;
      *(f32x4*)&Bs[br][bc] = *(const f32x4*)&W[(k0 + br) * C_ + bx * 64 + bc];
    }
    __syncthreads();
#pragma unroll
    for (int kq = 0; kq < 16; ++kq) {
      float a0 = As[kq][tr + 0], a1 = As[kq][tr + 1];
      float a2 = As[kq][tr + 2], a3 = As[kq][tr + 3];
      float b0 = Bs[kq][tc + 0], b1 = Bs[kq][tc + 1];
      accv[0][0] += a0 * b0; accv[0][1] += a0 * b1;
      accv[1][0] += a1 * b0; accv[1][1] += a1 * b1;
      accv[2][0] += a2 * b0; accv[2][1] += a2 * b1;
      accv[3][0] += a3 * b0; accv[3][1] += a3 * b1;
    }
    __syncthreads();
  }
#pragma unroll
  for (int rr = 0; rr < 4; ++rr)
#pragma unroll
    for (int cc = 0; cc < 2; ++cc) {
      int i = by * 32 + tr + rr;
      int col = bx * 64 + tc + cc;
      out[i * C_ + col] = accv[rr][cc] + b[col];
    }
}

// ---------------------------------------------------------------------------
extern "C" void kernel_launch(void* const* d_in, const int* in_sizes, int n_in,
                              void* d_out, int out_size, void* d_ws,
                              size_t ws_size, hipStream_t stream) {
  const float* x     = (const float*)d_in[0];
  const float* W_att = (const float*)d_in[1];
  const float* b_att = (const float*)d_in[2];
  const float* W_out = (const float*)d_in[3];
  const float* b_out = (const float*)d_in[4];

  char* ws = (char*)d_ws;
  float* y_acc          = (float*)(ws + 0);        // 524288 B
  float* l_acc          = (float*)(ws + 524288);   //   8192 B
  unsigned short* qB    = (unsigned short*)(ws + 532480);   // 262144 B
  float* kj             = (float*)(ws + 794624);   // 524288 B
  float* kk             = (float*)(ws + 1318912);  // 524288 B
  float* vj             = (float*)(ws + 1843200);  // 524288 B
  float* vkT            = (float*)(ws + 2367488);  // 524288 B
  float* yn             = (float*)(ws + 2891776);  // 524288 B

  hipMemsetAsync(y_acc, 0, 532480, stream);  // y_acc + l_acc
  proj_kernel<<<dim3(40, 8), 256, 0, stream>>>(x, W_att, b_att, qB, kj, kk, vj,
                                               vkT);
  flash3_kernel<<<dim3(8, 64), 256, 0, stream>>>(qB, kj, kk, vj, vkT, y_acc,
                                                 l_acc);
  norm_kernel<<<dim3(512), 256, 0, stream>>>(y_acc, l_acc, yn);
  out_gemm<<<dim3(8, 8), 256, 0, stream>>>(yn, W_out, b_out, (float*)d_out);
}